// Round 7
// baseline (218.741 us; speedup 1.0000x reference)
//
#include <hip/hip_runtime.h>
#include <math.h>

// Problem constants (match reference)
#define B_SZ 2
#define P_SZ 8192
#define K_NB 48
#define NRAD 8
#define NJ 2048          // 32 basis * 64 c_in
#define PTS 8            // points per block
#define GSTRIDE 2052     // G row stride (16B-aligned)
#define EPS_D 1e-8f

// ---- fused transpose: features [B][64][P] -> featT [B][P][64]  (blocks 0..255)
//      W [32][64 c][64 j] -> Wt [nj=n*64+j][64 c]                (blocks 256..287)
__global__ __launch_bounds__(256) void k_transpose(const float* __restrict__ f,
                                                   const float* __restrict__ w,
                                                   float* __restrict__ ft,
                                                   float* __restrict__ wt) {
    __shared__ float tile[64][65];
    int blk = blockIdx.x;
    int t = threadIdx.x;
    if (blk < 256) {
        int b = blk >> 7;                  // P/64 = 128
        int p0 = (blk & 127) << 6;
        {
            int pp = t & 63, cq = t >> 6;  // cq 0..3
#pragma unroll
            for (int i = 0; i < 16; ++i) {
                int c = cq * 16 + i;
                tile[c][pp] = f[((size_t)b * 64 + c) * P_SZ + p0 + pp];  // coalesced over p
            }
        }
        __syncthreads();
        {
            int cc = t & 63, pq = t >> 6;
#pragma unroll
            for (int i = 0; i < 16; ++i) {
                int p = pq * 16 + i;
                ft[((size_t)b * P_SZ + p0 + p) * 64 + cc] = tile[cc][p];  // coalesced over c
            }
        }
    } else {
        int n = blk - 256;  // 0..31
        {
            int jj = t & 63, cq = t >> 6;
#pragma unroll
            for (int i = 0; i < 16; ++i) {
                int c = cq * 16 + i;
                tile[c][jj] = w[((size_t)n * 64 + c) * 64 + jj];  // coalesced over j
            }
        }
        __syncthreads();
        {
            int cc = t & 63, jq = t >> 6;
#pragma unroll
            for (int i = 0; i < 16; ++i) {
                int j = jq * 16 + i;
                wt[((size_t)n * 64 + j) * 64 + cc] = tile[cc][j];  // coalesced over c
            }
        }
    }
}

// ---------------- main fused kernel ------------------------------------------
// block = 512 threads (8 waves), one wave per point in phase A.
// LDS: G[8][2052] f32 (65.7KB) + sh[8][48][4] (6.1KB) + d (1.5KB) + nbrs
// (1.5KB) = 73.1KB -> 2 blocks/CU (LDS-wise).
//
// __launch_bounds__ history (measured):
//   (512,4) R4: allocator squeezed VGPR 124->64, massive scratch spills
//               (894MB WRITE_SIZE), 372us. Second arg SQUEEZES regalloc.
//   (512,2) R5: VGPR=104, no spills, but OccupancyPercent pinned at 22%
//               (= 2 waves/EU = 1 block/CU) despite LDS and VGPR both
//               permitting 2 blocks. R1/R4/R5 all match "2nd arg is a HARD
//               waves-per-EU CAP on this toolchain", not just a minimum.
//   (512)   now: no waves-per-eu attribute -> no cap, no squeeze. Natural
//               pressure ~104 VGPR (measured) <= 128 -> 4 waves/SIMD -> the
//               LDS-permitted 2 blocks/CU should become resident.
__global__ __launch_bounds__(512) void k_main(const float* __restrict__ featT,
                                              const float* __restrict__ geometry,
                                              const int* __restrict__ neighbors,
                                              const float* __restrict__ rel_mask,
                                              const float* __restrict__ Wt,
                                              float* __restrict__ out) {
    __shared__ float G[PTS][GSTRIDE];
    __shared__ float sh_l[PTS][K_NB][4];
    __shared__ float d_l[PTS][K_NB];
    __shared__ int   nbrs_l[PTS][K_NB];

    const int t = threadIdx.x;
    const int blk = blockIdx.x;
    const int b = blk >> 10;                 // P/PTS = 1024 blocks per batch
    const int pt0 = (blk & 1023) * PTS;

    // ---- edge prep: distance + masked SH + neighbor idx ---------------------
    if (t < PTS * K_NB) {
        int pt = t / K_NB;
        int k = t - pt * K_NB;
        int p = pt0 + pt;
        size_t base = (size_t)b * P_SZ + p;
        int nb = neighbors[base * K_NB + k];
        const float* gp = &geometry[base * 3];
        const float* gn = &geometry[((size_t)b * P_SZ + nb) * 3];
        float rx = gn[0] - gp[0], ry = gn[1] - gp[1], rz = gn[2] - gp[2];
        float d = sqrtf(rx * rx + ry * ry + rz * rz);
        float mask = rel_mask[base * K_NB + k];
        float inv = (d > EPS_D) ? (1.0f / d) : 0.0f;   // matches jnp.where semantics
        sh_l[pt][k][0] = mask;
        sh_l[pt][k][1] = rx * inv * mask;
        sh_l[pt][k][2] = ry * inv * mask;
        sh_l[pt][k][3] = rz * inv * mask;
        d_l[pt][k] = d;
        nbrs_l[pt][k] = nb;
    }
    __syncthreads();

    // ---- phase A: G[pt][n*64+j] = sum_k basis[k][n] * feat[nbr_k][j] --------
    {
        const int pt = t >> 6;          // wave index == point
        const int ng = (t >> 3) & 7;    // radial index r; n0 = ng*4
        const int jg = t & 7;
        const int j0 = jg * 8;
        const float center = (float)ng * (2.0f / 7.0f);  // linspace(0,2,8)[ng]
        float acc[4][8];
#pragma unroll
        for (int s = 0; s < 4; ++s)
#pragma unroll
            for (int j = 0; j < 8; ++j) acc[s][j] = 0.0f;

        const float* fbase = featT + (size_t)b * P_SZ * 64;
#pragma unroll 4
        for (int k = 0; k < K_NB; ++k) {
            int nb = nbrs_l[pt][k];
            const float4* fv = (const float4*)(fbase + (size_t)nb * 64 + j0);
            float4 fA = fv[0];
            float4 fB = fv[1];
            float z = (d_l[pt][k] - center) * 4.0f;      // 1/SIGMA = 4
            float rad = __expf(-0.5f * z * z);
            float4 s4 = *(const float4*)&sh_l[pt][k][0];
            float bs[4] = {rad * s4.x, rad * s4.y, rad * s4.z, rad * s4.w};
            float fj[8] = {fA.x, fA.y, fA.z, fA.w, fB.x, fB.y, fB.z, fB.w};
#pragma unroll
            for (int s = 0; s < 4; ++s)
#pragma unroll
                for (int j = 0; j < 8; ++j) acc[s][j] += bs[s] * fj[j];
        }
        const int n0 = ng * 4;
#pragma unroll
        for (int s = 0; s < 4; ++s) {
            *(float4*)&G[pt][(n0 + s) * 64 + j0]     = make_float4(acc[s][0], acc[s][1], acc[s][2], acc[s][3]);
            *(float4*)&G[pt][(n0 + s) * 64 + j0 + 4] = make_float4(acc[s][4], acc[s][5], acc[s][6], acc[s][7]);
        }
    }
    __syncthreads();

    // ---- phase B: out[c][pt] = sum_nj Wt[nj][c] * G[pt][nj] -----------------
    // thread: cg = t&7 (8 c's), sg = t>>3 (64 slices of 32 nj). Rotation of
    // nj within the slice spreads the 8 in-wave slice groups across banks.
    float acc2[8][8];   // [ci][pt]
    {
        const int cg = t & 7;
        const int sg = t >> 3;
        const int c0 = cg * 8;
#pragma unroll
        for (int ci = 0; ci < 8; ++ci)
#pragma unroll
            for (int pt = 0; pt < 8; ++pt) acc2[ci][pt] = 0.0f;

        const int njbase = sg * 32;
        const int rot = (sg * 4) & 31;
#pragma unroll
        for (int it = 0; it < 8; ++it) {
            const int njo = njbase + ((it * 4 + rot) & 31);
            float4 g4[8];
#pragma unroll
            for (int pt = 0; pt < 8; ++pt) g4[pt] = *(const float4*)&G[pt][njo];
            float gf[8][4];
#pragma unroll
            for (int pt = 0; pt < 8; ++pt) {
                gf[pt][0] = g4[pt].x; gf[pt][1] = g4[pt].y;
                gf[pt][2] = g4[pt].z; gf[pt][3] = g4[pt].w;
            }
            float wf[4][8];
#pragma unroll
            for (int q = 0; q < 4; ++q) {
                const float4* wp = (const float4*)(Wt + (size_t)(njo + q) * 64 + c0);
                float4 w0 = wp[0], w1 = wp[1];
                wf[q][0] = w0.x; wf[q][1] = w0.y; wf[q][2] = w0.z; wf[q][3] = w0.w;
                wf[q][4] = w1.x; wf[q][5] = w1.y; wf[q][6] = w1.z; wf[q][7] = w1.w;
            }
#pragma unroll
            for (int q = 0; q < 4; ++q)
#pragma unroll
                for (int ci = 0; ci < 8; ++ci)
#pragma unroll
                    for (int pt = 0; pt < 8; ++pt)
                        acc2[ci][pt] += wf[q][ci] * gf[pt][q];
        }

        // in-wave butterfly over the 3 slice bits (lanes 8,16,32 apart)
#pragma unroll
        for (int off = 8; off <= 32; off <<= 1)
#pragma unroll
            for (int ci = 0; ci < 8; ++ci)
#pragma unroll
                for (int pt = 0; pt < 8; ++pt)
                    acc2[ci][pt] += __shfl_xor(acc2[ci][pt], off, 64);
    }
    __syncthreads();   // all G reads done -> safe to overlay partials on G

    // cross-wave reduction: 8 wave-partials per output, staged in dead G space
    float* partial = &G[0][0];   // 8 * 552 floats used << G capacity
    if (((t >> 3) & 7) == 0) {   // one lane-group per wave holds the wave sum
        const int cg = t & 7;
        const int w = t >> 6;
#pragma unroll
        for (int ci = 0; ci < 8; ++ci) {
            int c = cg * 8 + ci;
            int base = w * 552 + c * 8 + cg * 4;  // +cg*4 pad: spreads banks
            *(float4*)&partial[base]     = make_float4(acc2[ci][0], acc2[ci][1], acc2[ci][2], acc2[ci][3]);
            *(float4*)&partial[base + 4] = make_float4(acc2[ci][4], acc2[ci][5], acc2[ci][6], acc2[ci][7]);
        }
    }
    __syncthreads();
    {
        const int c = t >> 3, pt = t & 7;
        const int off = c * 8 + (c >> 3) * 4 + pt;
        float s = 0.0f;
#pragma unroll
        for (int w = 0; w < 8; ++w) s += partial[w * 552 + off];
        out[((size_t)b * 64 + c) * P_SZ + pt0 + pt] = s;
    }
}

extern "C" void kernel_launch(void* const* d_in, const int* in_sizes, int n_in,
                              void* d_out, int out_size, void* d_ws, size_t ws_size,
                              hipStream_t stream) {
    const float* features  = (const float*)d_in[0];
    const float* geometry  = (const float*)d_in[1];
    const int*   neighbors = (const int*)d_in[2];
    const float* rel_mask  = (const float*)d_in[3];
    const float* W         = (const float*)d_in[4];
    float* out = (float*)d_out;

    float* featT = (float*)d_ws;                                   // 4 MB
    float* Wt    = (float*)((char*)d_ws + (size_t)B_SZ * P_SZ * 64 * 4);  // 512 KB

    k_transpose<<<288, 256, 0, stream>>>(features, W, featT, Wt);
    k_main<<<B_SZ * (P_SZ / PTS), 512, 0, stream>>>(featT, geometry, neighbors,
                                                    rel_mask, Wt, out);
}

// Round 13
// 210.121 us; speedup vs baseline: 1.0410x; 1.0410x over previous
//
#include <hip/hip_runtime.h>
#include <math.h>

// Problem constants (match reference)
#define B_SZ 2
#define P_SZ 8192
#define K_NB 48
#define NRAD 8
#define NJ 2048          // 32 basis * 64 c_in
#define PTS 8            // points per block
#define GSTRIDE 2052     // G row stride (16B-aligned)
#define EPS_D 1e-8f

// ---- fused transpose: features [B][64][P] -> featT [B][P][64]  (blocks 0..255)
//      W [32][64 c][64 j] -> Wt [nj=n*64+j][64 c]                (blocks 256..287)
__global__ __launch_bounds__(256) void k_transpose(const float* __restrict__ f,
                                                   const float* __restrict__ w,
                                                   float* __restrict__ ft,
                                                   float* __restrict__ wt) {
    __shared__ float tile[64][65];
    int blk = blockIdx.x;
    int t = threadIdx.x;
    if (blk < 256) {
        int b = blk >> 7;                  // P/64 = 128
        int p0 = (blk & 127) << 6;
        {
            int pp = t & 63, cq = t >> 6;  // cq 0..3
#pragma unroll
            for (int i = 0; i < 16; ++i) {
                int c = cq * 16 + i;
                tile[c][pp] = f[((size_t)b * 64 + c) * P_SZ + p0 + pp];  // coalesced over p
            }
        }
        __syncthreads();
        {
            int cc = t & 63, pq = t >> 6;
#pragma unroll
            for (int i = 0; i < 16; ++i) {
                int p = pq * 16 + i;
                ft[((size_t)b * P_SZ + p0 + p) * 64 + cc] = tile[cc][p];  // coalesced over c
            }
        }
    } else {
        int n = blk - 256;  // 0..31
        {
            int jj = t & 63, cq = t >> 6;
#pragma unroll
            for (int i = 0; i < 16; ++i) {
                int c = cq * 16 + i;
                tile[c][jj] = w[((size_t)n * 64 + c) * 64 + jj];  // coalesced over j
            }
        }
        __syncthreads();
        {
            int cc = t & 63, jq = t >> 6;
#pragma unroll
            for (int i = 0; i < 16; ++i) {
                int j = jq * 16 + i;
                wt[((size_t)n * 64 + j) * 64 + cc] = tile[cc][j];  // coalesced over c
            }
        }
    }
}

// ---------------- main fused kernel ------------------------------------------
// block = 512 threads (8 waves), one wave per point.
//
// Occupancy model (measured R1/R4/R5/R7): wave-VGPR pow2 bucket decides
// blocks/CU: VGPR<=64 -> 2 blocks (occ 42%); 65..128 -> 1 block (occ 22%).
// __launch_bounds__ 2nd arg only squeezes regalloc (R4: 64 VGPR + spills).
// Phase B needs ~104 live VGPRs -> we operate at 2 waves/SIMD and buy ILP
// instead of TLP: phase A gathers go through global_load_lds (DMA, no
// dest VGPRs, counted vmcnt, wave-private double buffer) so L2 latency hides
// under the FMA stream instead of stalling it.
//
// LDS: G 65.7K + fstage 32K + sh 6.1K + d 1.5K + nbrs 1.5K = 106.9KB.
__global__ __launch_bounds__(512) void k_main(const float* __restrict__ featT,
                                              const float* __restrict__ geometry,
                                              const int* __restrict__ neighbors,
                                              const float* __restrict__ rel_mask,
                                              const float* __restrict__ Wt,
                                              float* __restrict__ out) {
    __shared__ float G[PTS][GSTRIDE];
    __shared__ float fstage[PTS][2][8][64];   // per-wave DMA staging, dbuf x 8 edges
    __shared__ float sh_l[PTS][K_NB][4];
    __shared__ float d_l[PTS][K_NB];
    __shared__ int   nbrs_l[PTS][K_NB];

    const int t = threadIdx.x;
    const int blk = blockIdx.x;
    const int b = blk >> 10;                 // P/PTS = 1024 blocks per batch
    const int pt0 = (blk & 1023) * PTS;

    // ---- edge prep: distance + masked SH + neighbor idx ---------------------
    if (t < PTS * K_NB) {
        int pt = t / K_NB;
        int k = t - pt * K_NB;
        int p = pt0 + pt;
        size_t base = (size_t)b * P_SZ + p;
        int nb = neighbors[base * K_NB + k];
        const float* gp = &geometry[base * 3];
        const float* gn = &geometry[((size_t)b * P_SZ + nb) * 3];
        float rx = gn[0] - gp[0], ry = gn[1] - gp[1], rz = gn[2] - gp[2];
        float d = sqrtf(rx * rx + ry * ry + rz * rz);
        float mask = rel_mask[base * K_NB + k];
        float inv = (d > EPS_D) ? (1.0f / d) : 0.0f;   // matches jnp.where semantics
        sh_l[pt][k][0] = mask;
        sh_l[pt][k][1] = rx * inv * mask;
        sh_l[pt][k][2] = ry * inv * mask;
        sh_l[pt][k][3] = rz * inv * mask;
        d_l[pt][k] = d;
        nbrs_l[pt][k] = nb;
    }
    __syncthreads();

    // ---- phase A: G[pt][n*64+j] = sum_k basis[k][n] * feat[nbr_k][j] --------
    // DMA-staged: one global_load_lds(16B) stages 4 edge rows (64 lanes x 16B
    // = 1KB, linear LDS dest = uniform base + lane*16). 2 instrs per 8-edge
    // group; double-buffered per wave; vmcnt(2) keeps next group in flight.
    {
        const int pt = t >> 6;          // wave index == point
        const int lane = t & 63;
        const int ng = (t >> 3) & 7;    // radial index r; n0 = ng*4
        const int jg = t & 7;
        const int j0 = jg * 8;
        const float center = (float)ng * (2.0f / 7.0f);  // linspace(0,2,8)[ng]
        float acc[4][8];
#pragma unroll
        for (int s = 0; s < 4; ++s)
#pragma unroll
            for (int j = 0; j < 8; ++j) acc[s][j] = 0.0f;

        const float* fbase = featT + (size_t)b * P_SZ * 64;
        const int esub = lane >> 4;     // which of 4 edges this lane stages
        const int coff = (lane & 15) * 4;  // float offset within the row

        // stage 8 edges of group g into buffer buf
        auto stage = [&](int g, int buf) {
            int e0 = g * 8 + esub;
            const float* gs0 = fbase + (size_t)nbrs_l[pt][e0] * 64 + coff;
            __builtin_amdgcn_global_load_lds(
                (const __attribute__((address_space(1))) unsigned int*)gs0,
                (__attribute__((address_space(3))) unsigned int*)&fstage[pt][buf][0][0],
                16, 0, 0);
            int e1 = e0 + 4;
            const float* gs1 = fbase + (size_t)nbrs_l[pt][e1] * 64 + coff;
            __builtin_amdgcn_global_load_lds(
                (const __attribute__((address_space(1))) unsigned int*)gs1,
                (__attribute__((address_space(3))) unsigned int*)&fstage[pt][buf][4][0],
                16, 0, 0);
        };

        stage(0, 0);
        for (int g = 0; g < 6; ++g) {           // 6 groups x 8 edges = 48
            const int buf = g & 1;
            if (g < 5) {
                stage(g + 1, buf ^ 1);
                asm volatile("s_waitcnt vmcnt(2)" ::: "memory");  // buf's 2 loads done
            } else {
                asm volatile("s_waitcnt vmcnt(0)" ::: "memory");
            }
#pragma unroll
            for (int ee = 0; ee < 8; ++ee) {
                const int e = g * 8 + ee;
                float z = (d_l[pt][e] - center) * 4.0f;   // 1/SIGMA = 4
                float rad = __expf(-0.5f * z * z);
                float4 s4 = *(const float4*)&sh_l[pt][e][0];
                float4 fA = *(const float4*)&fstage[pt][buf][ee][j0];
                float4 fB = *(const float4*)&fstage[pt][buf][ee][j0 + 4];
                float bs[4] = {rad * s4.x, rad * s4.y, rad * s4.z, rad * s4.w};
                float fj[8] = {fA.x, fA.y, fA.z, fA.w, fB.x, fB.y, fB.z, fB.w};
#pragma unroll
                for (int s = 0; s < 4; ++s)
#pragma unroll
                    for (int j = 0; j < 8; ++j) acc[s][j] += bs[s] * fj[j];
            }
        }
        const int n0 = ng * 4;
#pragma unroll
        for (int s = 0; s < 4; ++s) {
            *(float4*)&G[pt][(n0 + s) * 64 + j0]     = make_float4(acc[s][0], acc[s][1], acc[s][2], acc[s][3]);
            *(float4*)&G[pt][(n0 + s) * 64 + j0 + 4] = make_float4(acc[s][4], acc[s][5], acc[s][6], acc[s][7]);
        }
    }
    __syncthreads();

    // ---- phase B: out[c][pt] = sum_nj Wt[nj][c] * G[pt][nj] -----------------
    // thread: cg = t&7 (8 c's), sg = t>>3 (64 slices of 32 nj). Rotation of
    // nj within the slice spreads the 8 in-wave slice groups across banks.
    float acc2[8][8];   // [ci][pt]
    {
        const int cg = t & 7;
        const int sg = t >> 3;
        const int c0 = cg * 8;
#pragma unroll
        for (int ci = 0; ci < 8; ++ci)
#pragma unroll
            for (int pt = 0; pt < 8; ++pt) acc2[ci][pt] = 0.0f;

        const int njbase = sg * 32;
        const int rot = (sg * 4) & 31;
#pragma unroll
        for (int it = 0; it < 8; ++it) {
            const int njo = njbase + ((it * 4 + rot) & 31);
            float4 g4[8];
#pragma unroll
            for (int pt = 0; pt < 8; ++pt) g4[pt] = *(const float4*)&G[pt][njo];
            float gf[8][4];
#pragma unroll
            for (int pt = 0; pt < 8; ++pt) {
                gf[pt][0] = g4[pt].x; gf[pt][1] = g4[pt].y;
                gf[pt][2] = g4[pt].z; gf[pt][3] = g4[pt].w;
            }
            float wf[4][8];
#pragma unroll
            for (int q = 0; q < 4; ++q) {
                const float4* wp = (const float4*)(Wt + (size_t)(njo + q) * 64 + c0);
                float4 w0 = wp[0], w1 = wp[1];
                wf[q][0] = w0.x; wf[q][1] = w0.y; wf[q][2] = w0.z; wf[q][3] = w0.w;
                wf[q][4] = w1.x; wf[q][5] = w1.y; wf[q][6] = w1.z; wf[q][7] = w1.w;
            }
#pragma unroll
            for (int q = 0; q < 4; ++q)
#pragma unroll
                for (int ci = 0; ci < 8; ++ci)
#pragma unroll
                    for (int pt = 0; pt < 8; ++pt)
                        acc2[ci][pt] += wf[q][ci] * gf[pt][q];
        }

        // in-wave butterfly over the 3 slice bits (lanes 8,16,32 apart)
#pragma unroll
        for (int off = 8; off <= 32; off <<= 1)
#pragma unroll
            for (int ci = 0; ci < 8; ++ci)
#pragma unroll
                for (int pt = 0; pt < 8; ++pt)
                    acc2[ci][pt] += __shfl_xor(acc2[ci][pt], off, 64);
    }
    __syncthreads();   // all G reads done -> safe to overlay partials on G

    // cross-wave reduction: 8 wave-partials per output, staged in dead G space
    float* partial = &G[0][0];   // 8 * 552 floats used << G capacity
    if (((t >> 3) & 7) == 0) {   // one lane-group per wave holds the wave sum
        const int cg = t & 7;
        const int w = t >> 6;
#pragma unroll
        for (int ci = 0; ci < 8; ++ci) {
            int c = cg * 8 + ci;
            int base = w * 552 + c * 8 + cg * 4;  // +cg*4 pad: spreads banks
            *(float4*)&partial[base]     = make_float4(acc2[ci][0], acc2[ci][1], acc2[ci][2], acc2[ci][3]);
            *(float4*)&partial[base + 4] = make_float4(acc2[ci][4], acc2[ci][5], acc2[ci][6], acc2[ci][7]);
        }
    }
    __syncthreads();
    {
        const int c = t >> 3, pt = t & 7;
        const int off = c * 8 + (c >> 3) * 4 + pt;
        float s = 0.0f;
#pragma unroll
        for (int w = 0; w < 8; ++w) s += partial[w * 552 + off];
        out[((size_t)b * 64 + c) * P_SZ + pt0 + pt] = s;
    }
}

extern "C" void kernel_launch(void* const* d_in, const int* in_sizes, int n_in,
                              void* d_out, int out_size, void* d_ws, size_t ws_size,
                              hipStream_t stream) {
    const float* features  = (const float*)d_in[0];
    const float* geometry  = (const float*)d_in[1];
    const int*   neighbors = (const int*)d_in[2];
    const float* rel_mask  = (const float*)d_in[3];
    const float* W         = (const float*)d_in[4];
    float* out = (float*)d_out;

    float* featT = (float*)d_ws;                                   // 4 MB
    float* Wt    = (float*)((char*)d_ws + (size_t)B_SZ * P_SZ * 64 * 4);  // 512 KB

    k_transpose<<<288, 256, 0, stream>>>(features, W, featT, Wt);
    k_main<<<B_SZ * (P_SZ / PTS), 512, 0, stream>>>(featT, geometry, neighbors,
                                                    rel_mask, Wt, out);
}